// Round 18
// baseline (343.340 us; speedup 1.0000x reference)
//
#include <hip/hip_runtime.h>
#include <hip/hip_bf16.h>

#define S_DIM 4096
#define D_DIM 1024
#define F_DIM 4096

typedef unsigned short ushort_t;
typedef __attribute__((ext_vector_type(8))) short sh8;
typedef __attribute__((ext_vector_type(4))) short sh4;
typedef __attribute__((ext_vector_type(4))) float fx4;

__device__ __forceinline__ ushort_t f2bf(float f) {
    union { float f; unsigned u; } v; v.f = f;
    unsigned r = v.u + 0x7fffu + ((v.u >> 16) & 1u);
    return (ushort_t)(r >> 16);
}
__device__ __forceinline__ float bf2f(ushort_t u) {
    union { unsigned u; float f; } v; v.u = ((unsigned)u) << 16;
    return v.f;
}

typedef const __attribute__((address_space(1))) void* gvp;
typedef __attribute__((address_space(3))) void* svp;
__device__ __forceinline__ void gload_lds16(const void* g, void* l) {
    __builtin_amdgcn_global_load_lds((gvp)g, (svp)l, 16, 0, 0);
}

// Ablation ledger (final): bank-conflicts->0 null | occupancy x2 null |
// tile sweep flat (256^2 best) | 4-phase null | 8-phase null |
// single-barrier phase +2% | T1 XCD swizzle regressed (L3-fit) |
// prep merge -7us. GEMM structures FROZEN. Round-18: v-projection writes
// C^T directly (TRANSV epilogue: 4 consecutive rows/fragment = one packed
// 8B store) — eliminates the transpose_bf16 pass (16MB + launch gap).

// ---------------------------------------------------------------------------
// 128x128 bf16 GEMM (4 waves, 48KB, 3 blocks/CU) — round-7-verified pipeline.
// TRANSV: epilogue writes C^T ([N][M], bf16) instead of C.
// ---------------------------------------------------------------------------
#define BM 128
#define BN 128
#define BK 32
#define LDS_BUF 16384

template<bool BIAS, bool RELU, bool SCALE, bool OUTBF, bool SPLITK, bool TRANSV>
__device__ __forceinline__
void gemm_body(const ushort_t* A, const ushort_t* Bt,
               const float* bias,
               float* Cf, ushort_t* Cb,
               int M, int N, int K, int kBeg, int kEnd, float scale)
{
    __shared__ ushort_t lds[3 * (BM * BK + BN * BK)];   // 48 KiB
    const int tid = threadIdx.x;
    const int bm = blockIdx.x, bn = blockIdx.y;
    const int w  = tid >> 6, l = tid & 63;
    const int wm = w >> 1, wn = w & 1;

    fx4 acc[4][4] = {};

    const ushort_t* Ag = A  + (size_t)(bm * BM) * K;
    const ushort_t* Bg = Bt + (size_t)(bn * BN) * K;

    const int srow = tid >> 2;
    const int scs  = (tid & 3) ^ ((tid >> 3) & 3);

    auto stage = [&](int b, int k0) {
        char* base = (char*)lds + b * LDS_BUF;
        #pragma unroll
        for (int c = 0; c < 2; ++c) {
            int row = c * 64 + srow;
            gload_lds16(Ag + (size_t)row * K + k0 + scs * 8,
                        base + c * 4096 + tid * 16);
            gload_lds16(Bg + (size_t)row * K + k0 + scs * 8,
                        base + 8192 + c * 4096 + tid * 16);
        }
    };

    const int nt = (kEnd - kBeg) / BK;

    stage(0, kBeg);
    if (nt > 1) {
        stage(1, kBeg + BK);
        asm volatile("s_waitcnt vmcnt(4)" ::: "memory");
    } else {
        asm volatile("s_waitcnt vmcnt(0)" ::: "memory");
    }
    __builtin_amdgcn_s_barrier();
    __builtin_amdgcn_sched_barrier(0);

    const int rchunk = (l >> 4) ^ ((l >> 1) & 3);

    int cur = 0;
    for (int t = 0; t < nt; ++t) {
        int stg = cur + 2; if (stg >= 3) stg -= 3;
        if (t + 2 < nt) stage(stg, kBeg + (t + 2) * BK);

        char* lbase = (char*)lds + cur * LDS_BUF;
        sh8 af[4], bfr[4];
        #pragma unroll
        for (int q = 0; q < 4; ++q) {
            int ra = wm * 64 + q * 16 + (l & 15);
            af[q]  = *(const sh8*)(lbase + ra * 64 + rchunk * 16);
            int rb = wn * 64 + q * 16 + (l & 15);
            bfr[q] = *(const sh8*)(lbase + 8192 + rb * 64 + rchunk * 16);
        }
        #pragma unroll
        for (int i = 0; i < 4; ++i)
            #pragma unroll
            for (int j = 0; j < 4; ++j)
                acc[i][j] = __builtin_amdgcn_mfma_f32_16x16x32_bf16(
                                af[i], bfr[j], acc[i][j], 0, 0, 0);

        asm volatile("s_waitcnt lgkmcnt(0)" ::: "memory");
        if (t + 2 < nt)      asm volatile("s_waitcnt vmcnt(4)" ::: "memory");
        else if (t + 1 < nt) asm volatile("s_waitcnt vmcnt(0)" ::: "memory");
        if (t + 1 < nt) {
            __builtin_amdgcn_s_barrier();
            __builtin_amdgcn_sched_barrier(0);
        }
        cur = cur + 1; if (cur == 3) cur = 0;
    }

    if (SPLITK) Cb += (size_t)blockIdx.z * M * N;

    const int crow0 = bm * BM + wm * 64;
    const int ccol0 = bn * BN + wn * 64;
    #pragma unroll
    for (int i = 0; i < 4; ++i) {
        #pragma unroll
        for (int j = 0; j < 4; ++j) {
            int col = ccol0 + j * 16 + (l & 15);
            float bia = BIAS ? bias[col] : 0.f;
            if (TRANSV) {
                // C^T write: 4 consecutive rows at fixed col -> one 8B store
                int row0 = crow0 + i * 16 + (l >> 4) * 4;
                sh4 rv;
                #pragma unroll
                for (int r = 0; r < 4; ++r)
                    rv[r] = (short)f2bf(acc[i][j][r] + bia);
                *(sh4*)(Cb + (size_t)col * M + row0) = rv;
            } else {
                #pragma unroll
                for (int r = 0; r < 4; ++r) {
                    int row = crow0 + i * 16 + (l >> 4) * 4 + r;
                    float v = acc[i][j][r] + bia;
                    if (SCALE) v *= scale;
                    if (RELU) v = fmaxf(v, 0.f);
                    if (OUTBF) Cb[(size_t)row * N + col] = f2bf(v);
                    else       Cf[(size_t)row * N + col] = v;
                }
            }
        }
    }
}

template<bool BIAS, bool RELU, bool SCALE, bool OUTBF>
__global__ __launch_bounds__(256)
void gemm_bt(const ushort_t* __restrict__ A, const ushort_t* __restrict__ Bt,
             const float* __restrict__ bias,
             float* __restrict__ Cf, ushort_t* __restrict__ Cb,
             int M, int N, int K, float scale)
{
    gemm_body<BIAS, RELU, SCALE, OUTBF, false, false>(A, Bt, bias, Cf, Cb,
                                                      M, N, K, 0, K, scale);
}

__global__ __launch_bounds__(256)
void gemm_bt_sk(const ushort_t* __restrict__ A, const ushort_t* __restrict__ Bt,
                ushort_t* __restrict__ Cpart, int M, int N, int K, int Ks)
{
    int z = blockIdx.z;
    gemm_body<false, false, false, true, true, false>(
        A, Bt, nullptr, nullptr, Cpart,
        M, N, K, z * Ks, z * Ks + Ks, 1.f);
}

// batched q/k/v projections; v (z==2) writes its output TRANSPOSED [D][S]
__global__ __launch_bounds__(256)
void qkv_gemm(const ushort_t* qin, const ushort_t* kin, const ushort_t* vin,
              const ushort_t* WqT, const ushort_t* WkT, const ushort_t* WvT,
              const float* bq, const float* bk, const float* bv,
              ushort_t* qb, ushort_t* kb, ushort_t* vT, int M, int N, int K)
{
    if (blockIdx.z == 2) {
        gemm_body<true, false, false, true, false, true>(
            vin, WvT, bv, nullptr, vT, M, N, K, 0, K, 1.f);
        return;
    }
    const ushort_t* A; const ushort_t* Bt; const float* bias; ushort_t* C;
    if (blockIdx.z == 0) { A = qin; Bt = WqT; bias = bq; C = qb; }
    else                 { A = kin; Bt = WkT; bias = bk; C = kb; }
    gemm_body<true, false, false, true, false, false>(
        A, Bt, bias, nullptr, C, M, N, K, 0, K, 1.f);
}

// ---------------------------------------------------------------------------
// gemm8p: 256x256, BK=64, 512 thr (8 waves 2Mx4N), 128KB dynamic LDS.
// Round-16-verified single-barrier 8-phase; stage ledger
//   ph1: A0(t+1) ph2: A1(t+1) ph3: B0(t+2) ph4: B1(t+2)+vmcnt(4)
// (dbuf = t&1; epilogue degrades to vmcnt(0)); lgkmcnt(0) before each
// 16-MFMA setprio cluster. LDS chunk swizzle: physical16B = logical^(row&7),
// both sides (rule #21). FROZEN.
// ---------------------------------------------------------------------------
#define P_BM 256
#define P_BN 256
#define P_BK 64

template<bool BIAS, bool RELU, bool SCALE, bool MASKMUL, bool OUTBF, bool SPLITK>
__device__ __forceinline__
void gemm8p_body(const ushort_t* A, const ushort_t* Bt,
                 const float* bias, const float* mask,
                 float* Cf, ushort_t* Cb,
                 int M, int N, int K, int kBeg, int kEnd, float scale)
{
    extern __shared__ char plds[];          // 131072 B
    const int tid = threadIdx.x;            // 0..511
    const int bm = blockIdx.x, bn = blockIdx.y;
    const int w  = tid >> 6, l = tid & 63;
    const int wm = w >> 2, wn = w & 3;

    fx4 acc[8][4] = {};

    const ushort_t* Ag = A  + (size_t)(bm * P_BM) * K;
    const ushort_t* Bg = Bt + (size_t)(bn * P_BN) * K;

    const int s_lc = (tid & 7) ^ ((tid >> 3) & 7);   // stage logical chunk

    auto stageH = [&](int t, int op, int h) {
        int k0 = kBeg + t * P_BK;
        char* base = plds + (t & 1) * 65536 + op * 32768 + h * 16384;
        const ushort_t* G = op ? Bg : Ag;
        #pragma unroll
        for (int c = 0; c < 2; ++c) {
            int idx = c * 512 + tid;
            int row = idx >> 3;
            gload_lds16(G + (size_t)(h * 128 + row) * K + k0 + s_lc * 8,
                        base + idx * 16);
        }
    };

    auto ldA = [&](int d, int row, int kk) -> sh8 {
        int half = row >> 7, lr = row & 127;
        int chp = (kk * 4 + (l >> 4)) ^ (l & 7);
        return *(const sh8*)(plds + d * 65536 + half * 16384 + lr * 128 + chp * 16);
    };
    auto ldB = [&](int d, int row, int kk) -> sh8 {
        int half = row >> 7, lr = row & 127;
        int chp = (kk * 4 + (l >> 4)) ^ (l & 7);
        return *(const sh8*)(plds + d * 65536 + 32768 + half * 16384 + lr * 128 + chp * 16);
    };

    const int nt = (kEnd - kBeg) / P_BK;    // even by construction

    stageH(0, 0, 0); stageH(0, 0, 1); stageH(0, 1, 0); stageH(0, 1, 1);
    if (nt > 1) {
        stageH(1, 1, 0); stageH(1, 1, 1);
        asm volatile("s_waitcnt vmcnt(4)" ::: "memory");
    } else {
        asm volatile("s_waitcnt vmcnt(0)" ::: "memory");
    }
    __builtin_amdgcn_s_barrier();
    __builtin_amdgcn_sched_barrier(0);

    sh8 bfr[4][2];
    for (int u = 0; u < nt; u += 2) {
        #pragma unroll
        for (int hv = 0; hv < 2; ++hv) {
            const int t = u + hv;
            const int d = t & 1;
            #pragma unroll
            for (int q = 0; q < 4; ++q) {
                const int i0 = 2 * q;
                int ra = wm * 128 + i0 * 16 + (l & 15);
                sh8 a00 = ldA(d, ra, 0);
                sh8 a01 = ldA(d, ra, 1);
                sh8 a10 = ldA(d, ra + 16, 0);
                sh8 a11 = ldA(d, ra + 16, 1);
                if (q == 0) {
                    #pragma unroll
                    for (int j = 0; j < 4; ++j) {
                        int rb = wn * 64 + j * 16 + (l & 15);
                        bfr[j][0] = ldB(d, rb, 0);
                        bfr[j][1] = ldB(d, rb, 1);
                    }
                }
                if (q == 0)      { if (t + 1 < nt) stageH(t + 1, 0, 0); }
                else if (q == 1) { if (t + 1 < nt) stageH(t + 1, 0, 1); }
                else if (q == 2) { if (t + 2 < nt) stageH(t + 2, 1, 0); }
                else             { if (t + 2 < nt) stageH(t + 2, 1, 1); }

                asm volatile("s_waitcnt lgkmcnt(0)" ::: "memory");
                __builtin_amdgcn_sched_barrier(0);
                __builtin_amdgcn_s_setprio(1);
                #pragma unroll
                for (int j = 0; j < 4; ++j) {
                    acc[i0][j] = __builtin_amdgcn_mfma_f32_16x16x32_bf16(
                                     a00, bfr[j][0], acc[i0][j], 0, 0, 0);
                    acc[i0][j] = __builtin_amdgcn_mfma_f32_16x16x32_bf16(
                                     a01, bfr[j][1], acc[i0][j], 0, 0, 0);
                    acc[i0 + 1][j] = __builtin_amdgcn_mfma_f32_16x16x32_bf16(
                                     a10, bfr[j][0], acc[i0 + 1][j], 0, 0, 0);
                    acc[i0 + 1][j] = __builtin_amdgcn_mfma_f32_16x16x32_bf16(
                                     a11, bfr[j][1], acc[i0 + 1][j], 0, 0, 0);
                }
                __builtin_amdgcn_s_setprio(0);
                if (q == 3) {
                    if (t + 2 < nt)      asm volatile("s_waitcnt vmcnt(4)" ::: "memory");
                    else if (t + 1 < nt) asm volatile("s_waitcnt vmcnt(0)" ::: "memory");
                }
                __builtin_amdgcn_s_barrier();
                __builtin_amdgcn_sched_barrier(0);
            }
        }
    }

    if (SPLITK) Cb += (size_t)blockIdx.z * M * N;

    const int crow0 = bm * P_BM + wm * 128;
    const int ccol0 = bn * P_BN + wn * 64;
    #pragma unroll
    for (int i = 0; i < 8; ++i) {
        #pragma unroll
        for (int j = 0; j < 4; ++j) {
            int col = ccol0 + j * 16 + (l & 15);
            float bia = BIAS ? bias[col] : 0.f;
            #pragma unroll
            for (int r = 0; r < 4; ++r) {
                int row = crow0 + i * 16 + (l >> 4) * 4 + r;
                float v = acc[i][j][r] + bia;
                if (SCALE) v *= scale;
                if (MASKMUL) v *= mask[(size_t)row * N + col];
                if (RELU) v = fmaxf(v, 0.f);
                if (OUTBF) Cb[(size_t)row * N + col] = f2bf(v);
                else       Cf[(size_t)row * N + col] = v;
            }
        }
    }
}

template<bool BIAS, bool RELU, bool SCALE, bool MASKMUL, bool OUTBF>
__global__ __launch_bounds__(512, 1)
void gemm8p_bt(const ushort_t* __restrict__ A, const ushort_t* __restrict__ Bt,
               const float* __restrict__ bias, const float* __restrict__ mask,
               float* __restrict__ Cf, ushort_t* __restrict__ Cb,
               int M, int N, int K, float scale)
{
    gemm8p_body<BIAS, RELU, SCALE, MASKMUL, OUTBF, false>(
        A, Bt, bias, mask, Cf, Cb, M, N, K, 0, K, scale);
}

__global__ __launch_bounds__(512, 1)
void gemm8p_bt_sk(const ushort_t* __restrict__ A, const ushort_t* __restrict__ Bt,
                  ushort_t* __restrict__ Cpart, int M, int N, int K, int Ks)
{
    int z = blockIdx.z;
    gemm8p_body<false, false, false, false, true, true>(
        A, Bt, nullptr, nullptr, nullptr, Cpart,
        M, N, K, z * Ks, z * Ks + Ks, 1.f);
}

// sum NS bf16 partial matrices, write bf16
template<int NS>
__global__ __launch_bounds__(256)
void reduce_sk(const ushort_t* __restrict__ parts, ushort_t* __restrict__ ob,
               size_t MN)
{
    size_t idx = ((size_t)blockIdx.x * 256 + threadIdx.x) * 8;
    float s[8] = {0.f, 0.f, 0.f, 0.f, 0.f, 0.f, 0.f, 0.f};
    #pragma unroll
    for (int p = 0; p < NS; ++p) {
        sh8 v = *(const sh8*)(parts + (size_t)p * MN + idx);
        #pragma unroll
        for (int j = 0; j < 8; ++j) s[j] += bf2f((ushort_t)v[j]);
    }
    sh8 r;
    #pragma unroll
    for (int j = 0; j < 8; ++j) r[j] = (short)f2bf(s[j]);
    *(sh8*)(ob + idx) = r;
}

// ---------------------------------------------------------------------------
// prep_all: merged prologue — cvt(query,key,value->bf16) + 4x DxD weight
// transpose + W1T + W2T in ONE launch. Flat grid 18432 x 256 thr.
// ---------------------------------------------------------------------------
__global__ __launch_bounds__(256)
void prep_all(const float* q, const float* k, const float* v,
              ushort_t* oq, ushort_t* ok, ushort_t* ov,
              const float* w0, const float* w1, const float* w2, const float* w3,
              ushort_t* o0, ushort_t* o1, ushort_t* o2, ushort_t* o3,
              const float* W1, ushort_t* W1T,
              const float* W2, ushort_t* W2T)
{
    __shared__ float t[32][33];
    int b = blockIdx.x;

    if (b < 6144) {                       // elementwise f32 -> bf16
        int y = b >> 11, x = b & 2047;
        const float* in = (y == 0) ? q : (y == 1) ? k : v;
        ushort_t* out   = (y == 0) ? oq : (y == 1) ? ok : ov;
        int i = (x * 256 + threadIdx.x) * 8;
        const float4* p = (const float4*)(in + i);
        float4 a = p[0], c = p[1];
        sh8 r;
        r[0] = (short)f2bf(a.x); r[1] = (short)f2bf(a.y);
        r[2] = (short)f2bf(a.z); r[3] = (short)f2bf(a.w);
        r[4] = (short)f2bf(c.x); r[5] = (short)f2bf(c.y);
        r[6] = (short)f2bf(c.z); r[7] = (short)f2bf(c.w);
        *(sh8*)(out + i) = r;
        return;
    }

    const float* in; ushort_t* out; int R, C, bx, by;
    if (b < 10240) {                      // 4 DxD transposes
        int b2 = b - 6144;
        int z = b2 >> 10, xy = b2 & 1023;
        bx = xy & 31; by = xy >> 5;
        R = D_DIM; C = D_DIM;
        in  = (z == 0) ? w0 : (z == 1) ? w1 : (z == 2) ? w2 : w3;
        out = (z == 0) ? o0 : (z == 1) ? o1 : (z == 2) ? o2 : o3;
    } else if (b < 14336) {               // W1 [D][F] -> [F][D]
        int b3 = b - 10240;
        bx = b3 & 127; by = b3 >> 7;
        R = D_DIM; C = F_DIM;
        in = W1; out = W1T;
    } else {                              // W2 [F][D] -> [D][F]
        int b4 = b - 14336;
        bx = b4 & 31; by = b4 >> 5;
        R = F_DIM; C = D_DIM;
        in = W2; out = W2T;
    }

    int bc = bx * 32, br = by * 32;
    int tx = threadIdx.x & 31, ty = threadIdx.x >> 5;
    #pragma unroll
    for (int i = 0; i < 32; i += 8)
        t[ty + i][tx] = in[(size_t)(br + ty + i) * C + bc + tx];
    __syncthreads();
    #pragma unroll
    for (int i = 0; i < 32; i += 8)
        out[(size_t)(bc + ty + i) * R + br + tx] = f2bf(t[tx][ty + i]);
}

// ---------------------------------------------------------------------------
// Column softmax (axis 0) over m = masked scaled scores (bf16).
// Partials in [chunk][col] layout (coalesced both passes).
// ---------------------------------------------------------------------------
#define NCH 256
#define ROWS_PER_CH (S_DIM / NCH)   // 16

__global__ __launch_bounds__(256)
void smax_pass1(const ushort_t* __restrict__ m,
                float* __restrict__ pmax, float* __restrict__ psum)
{
    int c0 = (blockIdx.x * 256 + threadIdx.x) * 8;
    int chunk = blockIdx.y;
    int r0 = chunk * ROWS_PER_CH;

    float mx[8], sm[8];
    #pragma unroll
    for (int j = 0; j < 8; ++j) { mx[j] = -1e30f; sm[j] = 0.f; }

    for (int i = 0; i < ROWS_PER_CH; ++i) {
        size_t off = (size_t)(r0 + i) * S_DIM + c0;
        sh8 mv = *(const sh8*)(m + off);
        #pragma unroll
        for (int j = 0; j < 8; ++j) {
            float v = bf2f((ushort_t)mv[j]);
            float nm = fmaxf(mx[j], v);
            sm[j] = sm[j] * __expf(mx[j] - nm) + __expf(v - nm);
            mx[j] = nm;
        }
    }
    #pragma unroll
    for (int j = 0; j < 8; ++j) {
        pmax[(size_t)chunk * S_DIM + c0 + j] = mx[j];
        psum[(size_t)chunk * S_DIM + c0 + j] = sm[j];
    }
}

__global__ __launch_bounds__(256)
void smax_pass2(const float* __restrict__ pmax, const float* __restrict__ psum,
                float* __restrict__ cmax, float* __restrict__ cinv)
{
    int col = blockIdx.x * 256 + threadIdx.x;
    float mx = -1e30f, sm = 0.f;
    for (int c = 0; c < NCH; ++c) {
        float m2 = pmax[(size_t)c * S_DIM + col];
        float s2 = psum[(size_t)c * S_DIM + col];
        float nm = fmaxf(mx, m2);
        sm = sm * __expf(mx - nm) + s2 * __expf(m2 - nm);
        mx = nm;
    }
    cmax[col] = mx;
    cinv[col] = 1.f / sm;
}

__global__ __launch_bounds__(256)
void smax_pass3(const ushort_t* __restrict__ m,
                const float* __restrict__ cmax, const float* __restrict__ cinv,
                ushort_t* __restrict__ h)
{
    size_t idx = ((size_t)blockIdx.x * 256 + threadIdx.x) * 8;
    int col0 = (int)(idx & (S_DIM - 1));
    sh8 mv = *(const sh8*)(m + idx);
    sh8 r;
    #pragma unroll
    for (int j = 0; j < 8; ++j) {
        int c = col0 + j;
        float v = bf2f((ushort_t)mv[j]);
        r[j] = (short)f2bf(__expf(v - cmax[c]) * cinv[c]);
    }
    *(sh8*)(h + idx) = r;
}

// ---------------------------------------------------------------------------
// LayerNorm( sum(parts) + pbias + resid ) over D=1024, one row per block.
// ---------------------------------------------------------------------------
template<int NS, bool WB>
__global__ __launch_bounds__(256)
void add_ln_sk(const ushort_t* __restrict__ parts, const float* __restrict__ pbias,
               const float* __restrict__ resid, const float* __restrict__ g,
               const float* __restrict__ be,
               float* __restrict__ of, ushort_t* __restrict__ ob)
{
    const int D = D_DIM;
    const size_t SD = (size_t)S_DIM * D_DIM;
    int row = blockIdx.x, tid = threadIdx.x;
    size_t base = (size_t)row * D + tid * 4;

    float4 vr = *(const float4*)(resid + base);
    float4 vbi = ((const float4*)pbias)[tid];
    float x0 = vr.x + vbi.x, x1 = vr.y + vbi.y, x2 = vr.z + vbi.z, x3 = vr.w + vbi.w;
    #pragma unroll
    for (int p = 0; p < NS; ++p) {
        sh4 v = *(const sh4*)(parts + p * SD + base);
        x0 += bf2f((ushort_t)v[0]); x1 += bf2f((ushort_t)v[1]);
        x2 += bf2f((ushort_t)v[2]); x3 += bf2f((ushort_t)v[3]);
    }

    float s = x0 + x1 + x2 + x3;
    float q = x0 * x0 + x1 * x1 + x2 * x2 + x3 * x3;
    #pragma unroll
    for (int off = 32; off; off >>= 1) {
        s += __shfl_down(s, off);
        q += __shfl_down(q, off);
    }
    __shared__ float red[8];
    int w = tid >> 6, l = tid & 63;
    if (!l) { red[w] = s; red[4 + w] = q; }
    __syncthreads();
    s = red[0] + red[1] + red[2] + red[3];
    q = red[4] + red[5] + red[6] + red[7];
    float mu = s * (1.f / D);
    float rstd = rsqrtf(q * (1.f / D) - mu * mu + 1e-5f);
    float4 vg  = ((const float4*)g)[tid];
    float4 vbe = ((const float4*)be)[tid];
    float y0 = (x0 - mu) * rstd * vg.x + vbe.x;
    float y1 = (x1 - mu) * rstd * vg.y + vbe.y;
    float y2 = (x2 - mu) * rstd * vg.z + vbe.z;
    float y3 = (x3 - mu) * rstd * vg.w + vbe.w;
    float4 r; r.x = y0; r.y = y1; r.z = y2; r.w = y3;
    *(float4*)(of + base) = r;
    if (WB) {
        sh4 rb;
        rb[0] = (short)f2bf(y0); rb[1] = (short)f2bf(y1);
        rb[2] = (short)f2bf(y2); rb[3] = (short)f2bf(y3);
        *(sh4*)(ob + base) = rb;
    }
}

// ---------------------------------------------------------------------------
extern "C" void kernel_launch(void* const* d_in, const int* in_sizes, int n_in,
                              void* d_out, int out_size, void* d_ws, size_t ws_size,
                              hipStream_t stream)
{
    const float* query = (const float*)d_in[0];
    const float* key_  = (const float*)d_in[1];
    const float* value = (const float*)d_in[2];
    const float* mask  = (const float*)d_in[3];
    const float* Wq = (const float*)d_in[4];  const float* bq = (const float*)d_in[5];
    const float* Wk = (const float*)d_in[6];  const float* bk = (const float*)d_in[7];
    const float* Wv = (const float*)d_in[8];  const float* bv = (const float*)d_in[9];
    const float* Wo = (const float*)d_in[10]; const float* bo = (const float*)d_in[11];
    const float* g1 = (const float*)d_in[12]; const float* be1 = (const float*)d_in[13];
    const float* W1 = (const float*)d_in[14]; const float* bf1 = (const float*)d_in[15];
    const float* W2 = (const float*)d_in[16]; const float* bf2 = (const float*)d_in[17];
    const float* g2 = (const float*)d_in[18]; const float* be2 = (const float*)d_in[19];

    const size_t MB = 1ull << 20;
    char* ws = (char*)d_ws;
    ushort_t* WqT = (ushort_t*)(ws);             // [0,2)
    ushort_t* WkT = (ushort_t*)(ws + 2 * MB);    // [2,4)
    ushort_t* WvT = (ushort_t*)(ws + 4 * MB);    // [4,6)
    ushort_t* WoT = (ushort_t*)(ws + 6 * MB);    // [6,8)
    ushort_t* W1T = (ushort_t*)(ws + 8 * MB);    // [8,16)   [F][D]
    ushort_t* W2T = (ushort_t*)(ws + 16 * MB);   // [16,24)  [D][F]
    ushort_t* qin = (ushort_t*)(ws + 24 * MB);   // [24,32)
    ushort_t* kin = (ushort_t*)(ws + 32 * MB);   // [32,40)
    ushort_t* vin = (ushort_t*)(ws + 40 * MB);   // [40,48)
    ushort_t* qb  = (ushort_t*)(ws + 48 * MB);   // [48,56)
    ushort_t* kb  = (ushort_t*)(ws + 56 * MB);   // [56,64)
    ushort_t* vT  = (ushort_t*)(ws + 72 * MB);   // [72,80)  [D][S] (written by qkv z=2)
    ushort_t* msc = (ushort_t*)(ws + 80 * MB);   // [80,112) masked scaled scores
    ushort_t* hb  = (ushort_t*)(ws + 112 * MB);  // [112,144)
    float*   pmax = (float*)(ws + 144 * MB);     // [144,148) [NCH][S]
    float*   psum = (float*)(ws + 148 * MB);     // [148,152)
    float*   cmax = (float*)(ws + 152 * MB);
    float*   cinv = (float*)(ws + 152 * MB + 64 * 1024);
    // reused regions
    ushort_t* pts1  = (ushort_t*)(ws + 80 * MB); // h@v partials 4x8MB over msc
    ushort_t* apb   = (ushort_t*)(ws + 24 * MB); // attn_pre bf16 over qin
    ushort_t* pts2  = (ushort_t*)(ws + 80 * MB); // attn@Wo partials 2x8MB
    float*    n1f   = (float*)(ws + 48 * MB);    // over qb+kb
    ushort_t* n1b   = (ushort_t*)(ws + 64 * MB); // [64,72) (free region)
    ushort_t* mid   = (ushort_t*)(ws + 112 * MB);// [S][F] bf16 over hb
    ushort_t* pts3  = (ushort_t*)(ws + 80 * MB); // ff partials 4x8MB

    const int S = S_DIM, D = D_DIM, F = F_DIM;
    const size_t P_LDS = 131072;

    // 1. merged prologue: cvt x3 + all weight transposes (one launch)
    prep_all<<<18432, 256, 0, stream>>>(
        query, key_, value, qin, kin, vin,
        Wq, Wk, Wv, Wo, WqT, WkT, WvT, WoT,
        W1, W1T, W2, W2T);

    // 2. batched q,k,v projections; v written directly transposed [D][S]
    qkv_gemm<<<dim3(S / BM, D / BN, 3), 256, 0, stream>>>(
        qin, kin, vin, WqT, WkT, WvT, bq, bk, bv, qb, kb, vT, S, D, D);

    // 3. masked scaled scores — 8-phase 256² kernel, grid (16,16)
    gemm8p_bt<false, false, true, true, true>
        <<<dim3(S / P_BM, S / P_BN), 512, P_LDS, stream>>>(
        qb, kb, nullptr, mask, nullptr, msc, S, S, D, 0.03125f);

    // 4. column softmax (msc already masked)
    smax_pass1<<<dim3(S / 2048, NCH), 256, 0, stream>>>(msc, pmax, psum);
    smax_pass2<<<S / 256, 256, 0, stream>>>(pmax, psum, cmax, cinv);
    smax_pass3<<<(size_t)S * S / 8 / 256, 256, 0, stream>>>(msc, cmax, cinv, hb);

    // 5. attn_pre = h @ v — 8-phase 256², 4-way split-K
    gemm8p_bt_sk<<<dim3(S / P_BM, D / P_BN, 4), 512, P_LDS, stream>>>(
        hb, vT, pts1, S, D, S, S / 4);
    reduce_sk<4><<<S * D / 2048, 256, 0, stream>>>(pts1, apb, (size_t)S * D);

    // 6. attn partials = attn_pre @ Wo — 128², 2-way split-K
    gemm_bt_sk<<<dim3(S / BM, D / BN, 2), 256, 0, stream>>>(apb, WoT, pts2, S, D, D, D / 2);

    // 7. n1 = LN(sum(pts2) + bo + query)
    add_ln_sk<2, true><<<S, 256, 0, stream>>>(pts2, bo, query, g1, be1, n1f, n1b);

    // 8. mid = relu(n1 @ W1 + bf1) — 8-phase 256²
    gemm8p_bt<true, true, false, false, true>
        <<<dim3(S / P_BM, F / P_BN), 512, P_LDS, stream>>>(
        n1b, W1T, bf1, nullptr, nullptr, mid, S, F, D, 1.f);

    // 9. ff partials = mid @ W2 — 8-phase 256², 4-way split-K
    gemm8p_bt_sk<<<dim3(S / P_BM, D / P_BN, 4), 512, P_LDS, stream>>>(
        mid, W2T, pts3, S, D, F, F / 4);

    // 10. out = LN(sum(pts3) + bf2 + n1)
    add_ln_sk<4, false><<<S, 256, 0, stream>>>(pts3, bf2, n1f, g2, be2,
                                               (float*)d_out, nullptr);
}

// Round 19
// 324.314 us; speedup vs baseline: 1.0587x; 1.0587x over previous
//
#include <hip/hip_runtime.h>
#include <hip/hip_bf16.h>

#define S_DIM 4096
#define D_DIM 1024
#define F_DIM 4096

typedef unsigned short ushort_t;
typedef __attribute__((ext_vector_type(8))) short sh8;
typedef __attribute__((ext_vector_type(4))) short sh4;
typedef __attribute__((ext_vector_type(4))) float fx4;

__device__ __forceinline__ ushort_t f2bf(float f) {
    union { float f; unsigned u; } v; v.f = f;
    unsigned r = v.u + 0x7fffu + ((v.u >> 16) & 1u);
    return (ushort_t)(r >> 16);
}
__device__ __forceinline__ float bf2f(ushort_t u) {
    union { unsigned u; float f; } v; v.u = ((unsigned)u) << 16;
    return v.f;
}

typedef const __attribute__((address_space(1))) void* gvp;
typedef __attribute__((address_space(3))) void* svp;
__device__ __forceinline__ void gload_lds16(const void* g, void* l) {
    __builtin_amdgcn_global_load_lds((gvp)g, (svp)l, 16, 0, 0);
}

// Ledger: r18 lesson — TWO gemm_body instantiations in ONE kernel double the
// static __shared__ (2x48KB=96KB -> 1 blk/CU, qkv 25->70us). Fix: one
// instantiation per kernel (qk_gemm + vT_gemm). TRANSV epilogue itself is
// correct and keeps the transpose pass eliminated.

// ---------------------------------------------------------------------------
// 128x128 bf16 GEMM (4 waves, 48KB, 3 blocks/CU) — round-7-verified pipeline.
// TRANSV: epilogue writes C^T ([N][M], bf16).
// ---------------------------------------------------------------------------
#define BM 128
#define BN 128
#define BK 32
#define LDS_BUF 16384

template<bool BIAS, bool RELU, bool SCALE, bool OUTBF, bool SPLITK, bool TRANSV>
__device__ __forceinline__
void gemm_body(const ushort_t* A, const ushort_t* Bt,
               const float* bias,
               float* Cf, ushort_t* Cb,
               int M, int N, int K, int kBeg, int kEnd, float scale)
{
    __shared__ ushort_t lds[3 * (BM * BK + BN * BK)];   // 48 KiB
    const int tid = threadIdx.x;
    const int bm = blockIdx.x, bn = blockIdx.y;
    const int w  = tid >> 6, l = tid & 63;
    const int wm = w >> 1, wn = w & 1;

    fx4 acc[4][4] = {};

    const ushort_t* Ag = A  + (size_t)(bm * BM) * K;
    const ushort_t* Bg = Bt + (size_t)(bn * BN) * K;

    const int srow = tid >> 2;
    const int scs  = (tid & 3) ^ ((tid >> 3) & 3);

    auto stage = [&](int b, int k0) {
        char* base = (char*)lds + b * LDS_BUF;
        #pragma unroll
        for (int c = 0; c < 2; ++c) {
            int row = c * 64 + srow;
            gload_lds16(Ag + (size_t)row * K + k0 + scs * 8,
                        base + c * 4096 + tid * 16);
            gload_lds16(Bg + (size_t)row * K + k0 + scs * 8,
                        base + 8192 + c * 4096 + tid * 16);
        }
    };

    const int nt = (kEnd - kBeg) / BK;

    stage(0, kBeg);
    if (nt > 1) {
        stage(1, kBeg + BK);
        asm volatile("s_waitcnt vmcnt(4)" ::: "memory");
    } else {
        asm volatile("s_waitcnt vmcnt(0)" ::: "memory");
    }
    __builtin_amdgcn_s_barrier();
    __builtin_amdgcn_sched_barrier(0);

    const int rchunk = (l >> 4) ^ ((l >> 1) & 3);

    int cur = 0;
    for (int t = 0; t < nt; ++t) {
        int stg = cur + 2; if (stg >= 3) stg -= 3;
        if (t + 2 < nt) stage(stg, kBeg + (t + 2) * BK);

        char* lbase = (char*)lds + cur * LDS_BUF;
        sh8 af[4], bfr[4];
        #pragma unroll
        for (int q = 0; q < 4; ++q) {
            int ra = wm * 64 + q * 16 + (l & 15);
            af[q]  = *(const sh8*)(lbase + ra * 64 + rchunk * 16);
            int rb = wn * 64 + q * 16 + (l & 15);
            bfr[q] = *(const sh8*)(lbase + 8192 + rb * 64 + rchunk * 16);
        }
        #pragma unroll
        for (int i = 0; i < 4; ++i)
            #pragma unroll
            for (int j = 0; j < 4; ++j)
                acc[i][j] = __builtin_amdgcn_mfma_f32_16x16x32_bf16(
                                af[i], bfr[j], acc[i][j], 0, 0, 0);

        asm volatile("s_waitcnt lgkmcnt(0)" ::: "memory");
        if (t + 2 < nt)      asm volatile("s_waitcnt vmcnt(4)" ::: "memory");
        else if (t + 1 < nt) asm volatile("s_waitcnt vmcnt(0)" ::: "memory");
        if (t + 1 < nt) {
            __builtin_amdgcn_s_barrier();
            __builtin_amdgcn_sched_barrier(0);
        }
        cur = cur + 1; if (cur == 3) cur = 0;
    }

    if (SPLITK) Cb += (size_t)blockIdx.z * M * N;

    const int crow0 = bm * BM + wm * 64;
    const int ccol0 = bn * BN + wn * 64;
    #pragma unroll
    for (int i = 0; i < 4; ++i) {
        #pragma unroll
        for (int j = 0; j < 4; ++j) {
            int col = ccol0 + j * 16 + (l & 15);
            float bia = BIAS ? bias[col] : 0.f;
            if (TRANSV) {
                int row0 = crow0 + i * 16 + (l >> 4) * 4;
                sh4 rv;
                #pragma unroll
                for (int r = 0; r < 4; ++r)
                    rv[r] = (short)f2bf(acc[i][j][r] + bia);
                *(sh4*)(Cb + (size_t)col * M + row0) = rv;
            } else {
                #pragma unroll
                for (int r = 0; r < 4; ++r) {
                    int row = crow0 + i * 16 + (l >> 4) * 4 + r;
                    float v = acc[i][j][r] + bia;
                    if (SCALE) v *= scale;
                    if (RELU) v = fmaxf(v, 0.f);
                    if (OUTBF) Cb[(size_t)row * N + col] = f2bf(v);
                    else       Cf[(size_t)row * N + col] = v;
                }
            }
        }
    }
}

__global__ __launch_bounds__(256)
void gemm_bt_sk(const ushort_t* __restrict__ A, const ushort_t* __restrict__ Bt,
                ushort_t* __restrict__ Cpart, int M, int N, int K, int Ks)
{
    int z = blockIdx.z;
    gemm_body<false, false, false, true, true, false>(
        A, Bt, nullptr, nullptr, Cpart,
        M, N, K, z * Ks, z * Ks + Ks, 1.f);
}

// batched q,k projections (z selects operand set) — ONE instantiation only
__global__ __launch_bounds__(256)
void qk_gemm(const ushort_t* qin, const ushort_t* kin,
             const ushort_t* WqT, const ushort_t* WkT,
             const float* bq, const float* bk,
             ushort_t* qb, ushort_t* kb, int M, int N, int K)
{
    const ushort_t* A; const ushort_t* Bt; const float* bias; ushort_t* C;
    if (blockIdx.z == 0) { A = qin; Bt = WqT; bias = bq; C = qb; }
    else                 { A = kin; Bt = WkT; bias = bk; C = kb; }
    gemm_body<true, false, false, true, false, false>(
        A, Bt, bias, nullptr, C, M, N, K, 0, K, 1.f);
}

// v projection writing C^T [D][S] directly — ONE instantiation only
__global__ __launch_bounds__(256)
void vT_gemm(const ushort_t* vin, const ushort_t* WvT, const float* bv,
             ushort_t* vT, int M, int N, int K)
{
    gemm_body<true, false, false, true, false, true>(
        vin, WvT, bv, nullptr, vT, M, N, K, 0, K, 1.f);
}

// ---------------------------------------------------------------------------
// gemm8p: 256x256, BK=64, 512 thr (8 waves 2Mx4N), 128KB dynamic LDS.
// Round-16-verified single-barrier 8-phase; FROZEN.
// ---------------------------------------------------------------------------
#define P_BM 256
#define P_BN 256
#define P_BK 64

template<bool BIAS, bool RELU, bool SCALE, bool MASKMUL, bool OUTBF, bool SPLITK>
__device__ __forceinline__
void gemm8p_body(const ushort_t* A, const ushort_t* Bt,
                 const float* bias, const float* mask,
                 float* Cf, ushort_t* Cb,
                 int M, int N, int K, int kBeg, int kEnd, float scale)
{
    extern __shared__ char plds[];          // 131072 B
    const int tid = threadIdx.x;            // 0..511
    const int bm = blockIdx.x, bn = blockIdx.y;
    const int w  = tid >> 6, l = tid & 63;
    const int wm = w >> 2, wn = w & 3;

    fx4 acc[8][4] = {};

    const ushort_t* Ag = A  + (size_t)(bm * P_BM) * K;
    const ushort_t* Bg = Bt + (size_t)(bn * P_BN) * K;

    const int s_lc = (tid & 7) ^ ((tid >> 3) & 7);

    auto stageH = [&](int t, int op, int h) {
        int k0 = kBeg + t * P_BK;
        char* base = plds + (t & 1) * 65536 + op * 32768 + h * 16384;
        const ushort_t* G = op ? Bg : Ag;
        #pragma unroll
        for (int c = 0; c < 2; ++c) {
            int idx = c * 512 + tid;
            int row = idx >> 3;
            gload_lds16(G + (size_t)(h * 128 + row) * K + k0 + s_lc * 8,
                        base + idx * 16);
        }
    };

    auto ldA = [&](int d, int row, int kk) -> sh8 {
        int half = row >> 7, lr = row & 127;
        int chp = (kk * 4 + (l >> 4)) ^ (l & 7);
        return *(const sh8*)(plds + d * 65536 + half * 16384 + lr * 128 + chp * 16);
    };
    auto ldB = [&](int d, int row, int kk) -> sh8 {
        int half = row >> 7, lr = row & 127;
        int chp = (kk * 4 + (l >> 4)) ^ (l & 7);
        return *(const sh8*)(plds + d * 65536 + 32768 + half * 16384 + lr * 128 + chp * 16);
    };

    const int nt = (kEnd - kBeg) / P_BK;

    stageH(0, 0, 0); stageH(0, 0, 1); stageH(0, 1, 0); stageH(0, 1, 1);
    if (nt > 1) {
        stageH(1, 1, 0); stageH(1, 1, 1);
        asm volatile("s_waitcnt vmcnt(4)" ::: "memory");
    } else {
        asm volatile("s_waitcnt vmcnt(0)" ::: "memory");
    }
    __builtin_amdgcn_s_barrier();
    __builtin_amdgcn_sched_barrier(0);

    sh8 bfr[4][2];
    for (int u = 0; u < nt; u += 2) {
        #pragma unroll
        for (int hv = 0; hv < 2; ++hv) {
            const int t = u + hv;
            const int d = t & 1;
            #pragma unroll
            for (int q = 0; q < 4; ++q) {
                const int i0 = 2 * q;
                int ra = wm * 128 + i0 * 16 + (l & 15);
                sh8 a00 = ldA(d, ra, 0);
                sh8 a01 = ldA(d, ra, 1);
                sh8 a10 = ldA(d, ra + 16, 0);
                sh8 a11 = ldA(d, ra + 16, 1);
                if (q == 0) {
                    #pragma unroll
                    for (int j = 0; j < 4; ++j) {
                        int rb = wn * 64 + j * 16 + (l & 15);
                        bfr[j][0] = ldB(d, rb, 0);
                        bfr[j][1] = ldB(d, rb, 1);
                    }
                }
                if (q == 0)      { if (t + 1 < nt) stageH(t + 1, 0, 0); }
                else if (q == 1) { if (t + 1 < nt) stageH(t + 1, 0, 1); }
                else if (q == 2) { if (t + 2 < nt) stageH(t + 2, 1, 0); }
                else             { if (t + 2 < nt) stageH(t + 2, 1, 1); }

                asm volatile("s_waitcnt lgkmcnt(0)" ::: "memory");
                __builtin_amdgcn_sched_barrier(0);
                __builtin_amdgcn_s_setprio(1);
                #pragma unroll
                for (int j = 0; j < 4; ++j) {
                    acc[i0][j] = __builtin_amdgcn_mfma_f32_16x16x32_bf16(
                                     a00, bfr[j][0], acc[i0][j], 0, 0, 0);
                    acc[i0][j] = __builtin_amdgcn_mfma_f32_16x16x32_bf16(
                                     a01, bfr[j][1], acc[i0][j], 0, 0, 0);
                    acc[i0 + 1][j] = __builtin_amdgcn_mfma_f32_16x16x32_bf16(
                                     a10, bfr[j][0], acc[i0 + 1][j], 0, 0, 0);
                    acc[i0 + 1][j] = __builtin_amdgcn_mfma_f32_16x16x32_bf16(
                                     a11, bfr[j][1], acc[i0 + 1][j], 0, 0, 0);
                }
                __builtin_amdgcn_s_setprio(0);
                if (q == 3) {
                    if (t + 2 < nt)      asm volatile("s_waitcnt vmcnt(4)" ::: "memory");
                    else if (t + 1 < nt) asm volatile("s_waitcnt vmcnt(0)" ::: "memory");
                }
                __builtin_amdgcn_s_barrier();
                __builtin_amdgcn_sched_barrier(0);
            }
        }
    }

    if (SPLITK) Cb += (size_t)blockIdx.z * M * N;

    const int crow0 = bm * P_BM + wm * 128;
    const int ccol0 = bn * P_BN + wn * 64;
    #pragma unroll
    for (int i = 0; i < 8; ++i) {
        #pragma unroll
        for (int j = 0; j < 4; ++j) {
            int col = ccol0 + j * 16 + (l & 15);
            float bia = BIAS ? bias[col] : 0.f;
            #pragma unroll
            for (int r = 0; r < 4; ++r) {
                int row = crow0 + i * 16 + (l >> 4) * 4 + r;
                float v = acc[i][j][r] + bia;
                if (SCALE) v *= scale;
                if (MASKMUL) v *= mask[(size_t)row * N + col];
                if (RELU) v = fmaxf(v, 0.f);
                if (OUTBF) Cb[(size_t)row * N + col] = f2bf(v);
                else       Cf[(size_t)row * N + col] = v;
            }
        }
    }
}

template<bool BIAS, bool RELU, bool SCALE, bool MASKMUL, bool OUTBF>
__global__ __launch_bounds__(512, 1)
void gemm8p_bt(const ushort_t* __restrict__ A, const ushort_t* __restrict__ Bt,
               const float* __restrict__ bias, const float* __restrict__ mask,
               float* __restrict__ Cf, ushort_t* __restrict__ Cb,
               int M, int N, int K, float scale)
{
    gemm8p_body<BIAS, RELU, SCALE, MASKMUL, OUTBF, false>(
        A, Bt, bias, mask, Cf, Cb, M, N, K, 0, K, scale);
}

__global__ __launch_bounds__(512, 1)
void gemm8p_bt_sk(const ushort_t* __restrict__ A, const ushort_t* __restrict__ Bt,
                  ushort_t* __restrict__ Cpart, int M, int N, int K, int Ks)
{
    int z = blockIdx.z;
    gemm8p_body<false, false, false, false, true, true>(
        A, Bt, nullptr, nullptr, nullptr, Cpart,
        M, N, K, z * Ks, z * Ks + Ks, 1.f);
}

// sum NS bf16 partial matrices, write bf16
template<int NS>
__global__ __launch_bounds__(256)
void reduce_sk(const ushort_t* __restrict__ parts, ushort_t* __restrict__ ob,
               size_t MN)
{
    size_t idx = ((size_t)blockIdx.x * 256 + threadIdx.x) * 8;
    float s[8] = {0.f, 0.f, 0.f, 0.f, 0.f, 0.f, 0.f, 0.f};
    #pragma unroll
    for (int p = 0; p < NS; ++p) {
        sh8 v = *(const sh8*)(parts + (size_t)p * MN + idx);
        #pragma unroll
        for (int j = 0; j < 8; ++j) s[j] += bf2f((ushort_t)v[j]);
    }
    sh8 r;
    #pragma unroll
    for (int j = 0; j < 8; ++j) r[j] = (short)f2bf(s[j]);
    *(sh8*)(ob + idx) = r;
}

// ---------------------------------------------------------------------------
// prep_all: merged prologue — cvt x3 + 4x DxD transpose + W1T + W2T.
// Flat grid 18432 x 256 thr.
// ---------------------------------------------------------------------------
__global__ __launch_bounds__(256)
void prep_all(const float* q, const float* k, const float* v,
              ushort_t* oq, ushort_t* ok, ushort_t* ov,
              const float* w0, const float* w1, const float* w2, const float* w3,
              ushort_t* o0, ushort_t* o1, ushort_t* o2, ushort_t* o3,
              const float* W1, ushort_t* W1T,
              const float* W2, ushort_t* W2T)
{
    __shared__ float t[32][33];
    int b = blockIdx.x;

    if (b < 6144) {
        int y = b >> 11, x = b & 2047;
        const float* in = (y == 0) ? q : (y == 1) ? k : v;
        ushort_t* out   = (y == 0) ? oq : (y == 1) ? ok : ov;
        int i = (x * 256 + threadIdx.x) * 8;
        const float4* p = (const float4*)(in + i);
        float4 a = p[0], c = p[1];
        sh8 r;
        r[0] = (short)f2bf(a.x); r[1] = (short)f2bf(a.y);
        r[2] = (short)f2bf(a.z); r[3] = (short)f2bf(a.w);
        r[4] = (short)f2bf(c.x); r[5] = (short)f2bf(c.y);
        r[6] = (short)f2bf(c.z); r[7] = (short)f2bf(c.w);
        *(sh8*)(out + i) = r;
        return;
    }

    const float* in; ushort_t* out; int R, C, bx, by;
    if (b < 10240) {
        int b2 = b - 6144;
        int z = b2 >> 10, xy = b2 & 1023;
        bx = xy & 31; by = xy >> 5;
        R = D_DIM; C = D_DIM;
        in  = (z == 0) ? w0 : (z == 1) ? w1 : (z == 2) ? w2 : w3;
        out = (z == 0) ? o0 : (z == 1) ? o1 : (z == 2) ? o2 : o3;
    } else if (b < 14336) {
        int b3 = b - 10240;
        bx = b3 & 127; by = b3 >> 7;
        R = D_DIM; C = F_DIM;
        in = W1; out = W1T;
    } else {
        int b4 = b - 14336;
        bx = b4 & 31; by = b4 >> 5;
        R = F_DIM; C = D_DIM;
        in = W2; out = W2T;
    }

    int bc = bx * 32, br = by * 32;
    int tx = threadIdx.x & 31, ty = threadIdx.x >> 5;
    #pragma unroll
    for (int i = 0; i < 32; i += 8)
        t[ty + i][tx] = in[(size_t)(br + ty + i) * C + bc + tx];
    __syncthreads();
    #pragma unroll
    for (int i = 0; i < 32; i += 8)
        out[(size_t)(bc + ty + i) * R + br + tx] = f2bf(t[tx][ty + i]);
}

// ---------------------------------------------------------------------------
// Column softmax (axis 0) over m = masked scaled scores (bf16).
// ---------------------------------------------------------------------------
#define NCH 256
#define ROWS_PER_CH (S_DIM / NCH)   // 16

__global__ __launch_bounds__(256)
void smax_pass1(const ushort_t* __restrict__ m,
                float* __restrict__ pmax, float* __restrict__ psum)
{
    int c0 = (blockIdx.x * 256 + threadIdx.x) * 8;
    int chunk = blockIdx.y;
    int r0 = chunk * ROWS_PER_CH;

    float mx[8], sm[8];
    #pragma unroll
    for (int j = 0; j < 8; ++j) { mx[j] = -1e30f; sm[j] = 0.f; }

    for (int i = 0; i < ROWS_PER_CH; ++i) {
        size_t off = (size_t)(r0 + i) * S_DIM + c0;
        sh8 mv = *(const sh8*)(m + off);
        #pragma unroll
        for (int j = 0; j < 8; ++j) {
            float v = bf2f((ushort_t)mv[j]);
            float nm = fmaxf(mx[j], v);
            sm[j] = sm[j] * __expf(mx[j] - nm) + __expf(v - nm);
            mx[j] = nm;
        }
    }
    #pragma unroll
    for (int j = 0; j < 8; ++j) {
        pmax[(size_t)chunk * S_DIM + c0 + j] = mx[j];
        psum[(size_t)chunk * S_DIM + c0 + j] = sm[j];
    }
}

__global__ __launch_bounds__(256)
void smax_pass2(const float* __restrict__ pmax, const float* __restrict__ psum,
                float* __restrict__ cmax, float* __restrict__ cinv)
{
    int col = blockIdx.x * 256 + threadIdx.x;
    float mx = -1e30f, sm = 0.f;
    for (int c = 0; c < NCH; ++c) {
        float m2 = pmax[(size_t)c * S_DIM + col];
        float s2 = psum[(size_t)c * S_DIM + col];
        float nm = fmaxf(mx, m2);
        sm = sm * __expf(mx - nm) + s2 * __expf(m2 - nm);
        mx = nm;
    }
    cmax[col] = mx;
    cinv[col] = 1.f / sm;
}

__global__ __launch_bounds__(256)
void smax_pass3(const ushort_t* __restrict__ m,
                const float* __restrict__ cmax, const float* __restrict__ cinv,
                ushort_t* __restrict__ h)
{
    size_t idx = ((size_t)blockIdx.x * 256 + threadIdx.x) * 8;
    int col0 = (int)(idx & (S_DIM - 1));
    sh8 mv = *(const sh8*)(m + idx);
    sh8 r;
    #pragma unroll
    for (int j = 0; j < 8; ++j) {
        int c = col0 + j;
        float v = bf2f((ushort_t)mv[j]);
        r[j] = (short)f2bf(__expf(v - cmax[c]) * cinv[c]);
    }
    *(sh8*)(h + idx) = r;
}

// ---------------------------------------------------------------------------
// LayerNorm( sum(parts) + pbias + resid ) over D=1024, one row per block.
// ---------------------------------------------------------------------------
template<int NS, bool WB>
__global__ __launch_bounds__(256)
void add_ln_sk(const ushort_t* __restrict__ parts, const float* __restrict__ pbias,
               const float* __restrict__ resid, const float* __restrict__ g,
               const float* __restrict__ be,
               float* __restrict__ of, ushort_t* __restrict__ ob)
{
    const int D = D_DIM;
    const size_t SD = (size_t)S_DIM * D_DIM;
    int row = blockIdx.x, tid = threadIdx.x;
    size_t base = (size_t)row * D + tid * 4;

    float4 vr = *(const float4*)(resid + base);
    float4 vbi = ((const float4*)pbias)[tid];
    float x0 = vr.x + vbi.x, x1 = vr.y + vbi.y, x2 = vr.z + vbi.z, x3 = vr.w + vbi.w;
    #pragma unroll
    for (int p = 0; p < NS; ++p) {
        sh4 v = *(const sh4*)(parts + p * SD + base);
        x0 += bf2f((ushort_t)v[0]); x1 += bf2f((ushort_t)v[1]);
        x2 += bf2f((ushort_t)v[2]); x3 += bf2f((ushort_t)v[3]);
    }

    float s = x0 + x1 + x2 + x3;
    float q = x0 * x0 + x1 * x1 + x2 * x2 + x3 * x3;
    #pragma unroll
    for (int off = 32; off; off >>= 1) {
        s += __shfl_down(s, off);
        q += __shfl_down(q, off);
    }
    __shared__ float red[8];
    int w = tid >> 6, l = tid & 63;
    if (!l) { red[w] = s; red[4 + w] = q; }
    __syncthreads();
    s = red[0] + red[1] + red[2] + red[3];
    q = red[4] + red[5] + red[6] + red[7];
    float mu = s * (1.f / D);
    float rstd = rsqrtf(q * (1.f / D) - mu * mu + 1e-5f);
    float4 vg  = ((const float4*)g)[tid];
    float4 vbe = ((const float4*)be)[tid];
    float y0 = (x0 - mu) * rstd * vg.x + vbe.x;
    float y1 = (x1 - mu) * rstd * vg.y + vbe.y;
    float y2 = (x2 - mu) * rstd * vg.z + vbe.z;
    float y3 = (x3 - mu) * rstd * vg.w + vbe.w;
    float4 r; r.x = y0; r.y = y1; r.z = y2; r.w = y3;
    *(float4*)(of + base) = r;
    if (WB) {
        sh4 rb;
        rb[0] = (short)f2bf(y0); rb[1] = (short)f2bf(y1);
        rb[2] = (short)f2bf(y2); rb[3] = (short)f2bf(y3);
        *(sh4*)(ob + base) = rb;
    }
}

// ---------------------------------------------------------------------------
extern "C" void kernel_launch(void* const* d_in, const int* in_sizes, int n_in,
                              void* d_out, int out_size, void* d_ws, size_t ws_size,
                              hipStream_t stream)
{
    const float* query = (const float*)d_in[0];
    const float* key_  = (const float*)d_in[1];
    const float* value = (const float*)d_in[2];
    const float* mask  = (const float*)d_in[3];
    const float* Wq = (const float*)d_in[4];  const float* bq = (const float*)d_in[5];
    const float* Wk = (const float*)d_in[6];  const float* bk = (const float*)d_in[7];
    const float* Wv = (const float*)d_in[8];  const float* bv = (const float*)d_in[9];
    const float* Wo = (const float*)d_in[10]; const float* bo = (const float*)d_in[11];
    const float* g1 = (const float*)d_in[12]; const float* be1 = (const float*)d_in[13];
    const float* W1 = (const float*)d_in[14]; const float* bf1 = (const float*)d_in[15];
    const float* W2 = (const float*)d_in[16]; const float* bf2 = (const float*)d_in[17];
    const float* g2 = (const float*)d_in[18]; const float* be2 = (const float*)d_in[19];

    const size_t MB = 1ull << 20;
    char* ws = (char*)d_ws;
    ushort_t* WqT = (ushort_t*)(ws);             // [0,2)
    ushort_t* WkT = (ushort_t*)(ws + 2 * MB);    // [2,4)
    ushort_t* WvT = (ushort_t*)(ws + 4 * MB);    // [4,6)
    ushort_t* WoT = (ushort_t*)(ws + 6 * MB);    // [6,8)
    ushort_t* W1T = (ushort_t*)(ws + 8 * MB);    // [8,16)   [F][D]
    ushort_t* W2T = (ushort_t*)(ws + 16 * MB);   // [16,24)  [D][F]
    ushort_t* qin = (ushort_t*)(ws + 24 * MB);   // [24,32)
    ushort_t* kin = (ushort_t*)(ws + 32 * MB);   // [32,40)
    ushort_t* vin = (ushort_t*)(ws + 40 * MB);   // [40,48)
    ushort_t* qb  = (ushort_t*)(ws + 48 * MB);   // [48,56)
    ushort_t* kb  = (ushort_t*)(ws + 56 * MB);   // [56,64)
    ushort_t* vT  = (ushort_t*)(ws + 72 * MB);   // [72,80)  [D][S] (from vT_gemm)
    ushort_t* msc = (ushort_t*)(ws + 80 * MB);   // [80,112) masked scaled scores
    ushort_t* hb  = (ushort_t*)(ws + 112 * MB);  // [112,144)
    float*   pmax = (float*)(ws + 144 * MB);     // [144,148) [NCH][S]
    float*   psum = (float*)(ws + 148 * MB);     // [148,152)
    float*   cmax = (float*)(ws + 152 * MB);
    float*   cinv = (float*)(ws + 152 * MB + 64 * 1024);
    // reused regions
    ushort_t* pts1  = (ushort_t*)(ws + 80 * MB); // h@v partials 4x8MB over msc
    ushort_t* apb   = (ushort_t*)(ws + 24 * MB); // attn_pre bf16 over qin
    ushort_t* pts2  = (ushort_t*)(ws + 80 * MB); // attn@Wo partials 2x8MB
    float*    n1f   = (float*)(ws + 48 * MB);    // over qb+kb
    ushort_t* n1b   = (ushort_t*)(ws + 64 * MB); // [64,72)
    ushort_t* mid   = (ushort_t*)(ws + 112 * MB);// [S][F] bf16 over hb
    ushort_t* pts3  = (ushort_t*)(ws + 80 * MB); // ff partials 4x8MB

    const int S = S_DIM, D = D_DIM, F = F_DIM;
    const size_t P_LDS = 131072;

    // 1. merged prologue: cvt x3 + all weight transposes (one launch)
    prep_all<<<18432, 256, 0, stream>>>(
        query, key_, value, qin, kin, vin,
        Wq, Wk, Wv, Wo, WqT, WkT, WvT, WoT,
        W1, W1T, W2, W2T);

    // 2a. q,k projections (batched, TRANSV=false instantiation only)
    qk_gemm<<<dim3(S / BM, D / BN, 2), 256, 0, stream>>>(
        qin, kin, WqT, WkT, bq, bk, qb, kb, S, D, D);
    // 2b. v projection writing v^T [D][S] directly (TRANSV=true only)
    vT_gemm<<<dim3(S / BM, D / BN), 256, 0, stream>>>(
        vin, WvT, bv, vT, S, D, D);

    // 3. masked scaled scores — 8-phase 256² kernel, grid (16,16)
    gemm8p_bt<false, false, true, true, true>
        <<<dim3(S / P_BM, S / P_BN), 512, P_LDS, stream>>>(
        qb, kb, nullptr, mask, nullptr, msc, S, S, D, 0.03125f);

    // 4. column softmax (msc already masked)
    smax_pass1<<<dim3(S / 2048, NCH), 256, 0, stream>>>(msc, pmax, psum);
    smax_pass2<<<S / 256, 256, 0, stream>>>(pmax, psum, cmax, cinv);
    smax_pass3<<<(size_t)S * S / 8 / 256, 256, 0, stream>>>(msc, cmax, cinv, hb);

    // 5. attn_pre = h @ v — 8-phase 256², 4-way split-K
    gemm8p_bt_sk<<<dim3(S / P_BM, D / P_BN, 4), 512, P_LDS, stream>>>(
        hb, vT, pts1, S, D, S, S / 4);
    reduce_sk<4><<<S * D / 2048, 256, 0, stream>>>(pts1, apb, (size_t)S * D);

    // 6. attn partials = attn_pre @ Wo — 128², 2-way split-K
    gemm_bt_sk<<<dim3(S / BM, D / BN, 2), 256, 0, stream>>>(apb, WoT, pts2, S, D, D, D / 2);

    // 7. n1 = LN(sum(pts2) + bo + query)
    add_ln_sk<2, true><<<S, 256, 0, stream>>>(pts2, bo, query, g1, be1, n1f, n1b);

    // 8. mid = relu(n1 @ W1 + bf1) — 8-phase 256²
    gemm8p_bt<true, true, false, false, true>
        <<<dim3(S / P_BM, F / P_BN), 512, P_LDS, stream>>>(
        n1b, W1T, bf1, nullptr, nullptr, mid, S, F, D, 1.f);

    // 9. ff partials = mid @ W2 — 8-phase 256², 4-way split-K
    gemm8p_bt_sk<<<dim3(S / P_BM, D / P_BN, 4), 512, P_LDS, stream>>>(
        mid, W2T, pts3, S, D, F, F / 4);

    // 10. out = LN(sum(pts3) + bf2 + n1)
    add_ln_sk<4, false><<<S, 256, 0, stream>>>(pts3, bf2, n1f, g2, be2,
                                               (float*)d_out, nullptr);
}

// Round 20
// 317.597 us; speedup vs baseline: 1.0811x; 1.0211x over previous
//
#include <hip/hip_runtime.h>
#include <hip/hip_bf16.h>

#define S_DIM 4096
#define D_DIM 1024
#define F_DIM 4096

typedef unsigned short ushort_t;
typedef __attribute__((ext_vector_type(8))) short sh8;
typedef __attribute__((ext_vector_type(4))) short sh4;
typedef __attribute__((ext_vector_type(4))) float fx4;

__device__ __forceinline__ ushort_t f2bf(float f) {
    union { float f; unsigned u; } v; v.f = f;
    unsigned r = v.u + 0x7fffu + ((v.u >> 16) & 1u);
    return (ushort_t)(r >> 16);
}
__device__ __forceinline__ float bf2f(ushort_t u) {
    union { unsigned u; float f; } v; v.u = ((unsigned)u) << 16;
    return v.f;
}

typedef const __attribute__((address_space(1))) void* gvp;
typedef __attribute__((address_space(3))) void* svp;
__device__ __forceinline__ void gload_lds16(const void* g, void* l) {
    __builtin_amdgcn_global_load_lds((gvp)g, (svp)l, 16, 0, 0);
}

// FINAL (round-20): exact revert to the round-17 best (318.2us measured).
// Ledger: bank-conflicts->0 null | occupancy x2 null | tile sweep flat |
// 4-phase null | 8-phase null | single-barrier +2% | T1 swizzle regressed |
// prep merge -7us | TRANSV wash (r18/r19). All structures FROZEN.

// ---------------------------------------------------------------------------
// 128x128 bf16 GEMM (4 waves, 48KB, 3 blocks/CU) — round-7-verified pipeline.
// Used for qkv projections and attn@Wo.
// ---------------------------------------------------------------------------
#define BM 128
#define BN 128
#define BK 32
#define LDS_BUF 16384

template<bool BIAS, bool RELU, bool SCALE, bool OUTBF, bool SPLITK>
__device__ __forceinline__
void gemm_body(const ushort_t* A, const ushort_t* Bt,
               const float* bias,
               float* Cf, ushort_t* Cb,
               int M, int N, int K, int kBeg, int kEnd, float scale)
{
    __shared__ ushort_t lds[3 * (BM * BK + BN * BK)];   // 48 KiB
    const int tid = threadIdx.x;
    const int bm = blockIdx.x, bn = blockIdx.y;
    const int w  = tid >> 6, l = tid & 63;
    const int wm = w >> 1, wn = w & 1;

    fx4 acc[4][4] = {};

    const ushort_t* Ag = A  + (size_t)(bm * BM) * K;
    const ushort_t* Bg = Bt + (size_t)(bn * BN) * K;

    const int srow = tid >> 2;
    const int scs  = (tid & 3) ^ ((tid >> 3) & 3);

    auto stage = [&](int b, int k0) {
        char* base = (char*)lds + b * LDS_BUF;
        #pragma unroll
        for (int c = 0; c < 2; ++c) {
            int row = c * 64 + srow;
            gload_lds16(Ag + (size_t)row * K + k0 + scs * 8,
                        base + c * 4096 + tid * 16);
            gload_lds16(Bg + (size_t)row * K + k0 + scs * 8,
                        base + 8192 + c * 4096 + tid * 16);
        }
    };

    const int nt = (kEnd - kBeg) / BK;

    stage(0, kBeg);
    if (nt > 1) {
        stage(1, kBeg + BK);
        asm volatile("s_waitcnt vmcnt(4)" ::: "memory");
    } else {
        asm volatile("s_waitcnt vmcnt(0)" ::: "memory");
    }
    __builtin_amdgcn_s_barrier();
    __builtin_amdgcn_sched_barrier(0);

    const int rchunk = (l >> 4) ^ ((l >> 1) & 3);

    int cur = 0;
    for (int t = 0; t < nt; ++t) {
        int stg = cur + 2; if (stg >= 3) stg -= 3;
        if (t + 2 < nt) stage(stg, kBeg + (t + 2) * BK);

        char* lbase = (char*)lds + cur * LDS_BUF;
        sh8 af[4], bfr[4];
        #pragma unroll
        for (int q = 0; q < 4; ++q) {
            int ra = wm * 64 + q * 16 + (l & 15);
            af[q]  = *(const sh8*)(lbase + ra * 64 + rchunk * 16);
            int rb = wn * 64 + q * 16 + (l & 15);
            bfr[q] = *(const sh8*)(lbase + 8192 + rb * 64 + rchunk * 16);
        }
        #pragma unroll
        for (int i = 0; i < 4; ++i)
            #pragma unroll
            for (int j = 0; j < 4; ++j)
                acc[i][j] = __builtin_amdgcn_mfma_f32_16x16x32_bf16(
                                af[i], bfr[j], acc[i][j], 0, 0, 0);

        asm volatile("s_waitcnt lgkmcnt(0)" ::: "memory");
        if (t + 2 < nt)      asm volatile("s_waitcnt vmcnt(4)" ::: "memory");
        else if (t + 1 < nt) asm volatile("s_waitcnt vmcnt(0)" ::: "memory");
        if (t + 1 < nt) {
            __builtin_amdgcn_s_barrier();
            __builtin_amdgcn_sched_barrier(0);
        }
        cur = cur + 1; if (cur == 3) cur = 0;
    }

    if (SPLITK) Cb += (size_t)blockIdx.z * M * N;

    const int crow0 = bm * BM + wm * 64;
    const int ccol0 = bn * BN + wn * 64;
    #pragma unroll
    for (int i = 0; i < 4; ++i) {
        #pragma unroll
        for (int j = 0; j < 4; ++j) {
            int col = ccol0 + j * 16 + (l & 15);
            float bia = BIAS ? bias[col] : 0.f;
            #pragma unroll
            for (int r = 0; r < 4; ++r) {
                int row = crow0 + i * 16 + (l >> 4) * 4 + r;
                float v = acc[i][j][r] + bia;
                if (SCALE) v *= scale;
                if (RELU) v = fmaxf(v, 0.f);
                if (OUTBF) Cb[(size_t)row * N + col] = f2bf(v);
                else       Cf[(size_t)row * N + col] = v;
            }
        }
    }
}

template<bool BIAS, bool RELU, bool SCALE, bool OUTBF>
__global__ __launch_bounds__(256)
void gemm_bt(const ushort_t* __restrict__ A, const ushort_t* __restrict__ Bt,
             const float* __restrict__ bias,
             float* __restrict__ Cf, ushort_t* __restrict__ Cb,
             int M, int N, int K, float scale)
{
    gemm_body<BIAS, RELU, SCALE, OUTBF, false>(A, Bt, bias, Cf, Cb,
                                               M, N, K, 0, K, scale);
}

__global__ __launch_bounds__(256)
void gemm_bt_sk(const ushort_t* __restrict__ A, const ushort_t* __restrict__ Bt,
                ushort_t* __restrict__ Cpart, int M, int N, int K, int Ks)
{
    int z = blockIdx.z;
    gemm_body<false, false, false, true, true>(A, Bt, nullptr,
                                               nullptr, Cpart,
                                               M, N, K, z * Ks, z * Ks + Ks, 1.f);
}

__global__ __launch_bounds__(256)
void qkv_gemm(const ushort_t* qin, const ushort_t* kin, const ushort_t* vin,
              const ushort_t* WqT, const ushort_t* WkT, const ushort_t* WvT,
              const float* bq, const float* bk, const float* bv,
              ushort_t* qb, ushort_t* kb, ushort_t* vb, int M, int N, int K)
{
    const ushort_t* A; const ushort_t* Bt; const float* bias; ushort_t* C;
    if (blockIdx.z == 0)      { A = qin; Bt = WqT; bias = bq; C = qb; }
    else if (blockIdx.z == 1) { A = kin; Bt = WkT; bias = bk; C = kb; }
    else                      { A = vin; Bt = WvT; bias = bv; C = vb; }
    gemm_body<true, false, false, true, false>(A, Bt, bias,
                                               nullptr, C, M, N, K, 0, K, 1.f);
}

// ---------------------------------------------------------------------------
// gemm8p: 256x256, BK=64, 512 thr (8 waves 2Mx4N), 128KB dynamic LDS.
// Round-16-verified single-barrier 8-phase; stage ledger
//   ph1: A0(t+1) ph2: A1(t+1) ph3: B0(t+2) ph4: B1(t+2)+vmcnt(4)
// (dbuf = t&1; epilogue degrades to vmcnt(0)); lgkmcnt(0) before each
// 16-MFMA setprio cluster. LDS chunk swizzle: physical16B = logical^(row&7),
// both sides (rule #21). FROZEN.
// ---------------------------------------------------------------------------
#define P_BM 256
#define P_BN 256
#define P_BK 64

template<bool BIAS, bool RELU, bool SCALE, bool MASKMUL, bool OUTBF, bool SPLITK>
__device__ __forceinline__
void gemm8p_body(const ushort_t* A, const ushort_t* Bt,
                 const float* bias, const float* mask,
                 float* Cf, ushort_t* Cb,
                 int M, int N, int K, int kBeg, int kEnd, float scale)
{
    extern __shared__ char plds[];          // 131072 B
    const int tid = threadIdx.x;            // 0..511
    const int bm = blockIdx.x, bn = blockIdx.y;
    const int w  = tid >> 6, l = tid & 63;
    const int wm = w >> 2, wn = w & 3;

    fx4 acc[8][4] = {};

    const ushort_t* Ag = A  + (size_t)(bm * P_BM) * K;
    const ushort_t* Bg = Bt + (size_t)(bn * P_BN) * K;

    const int s_lc = (tid & 7) ^ ((tid >> 3) & 7);   // stage logical chunk

    auto stageH = [&](int t, int op, int h) {
        int k0 = kBeg + t * P_BK;
        char* base = plds + (t & 1) * 65536 + op * 32768 + h * 16384;
        const ushort_t* G = op ? Bg : Ag;
        #pragma unroll
        for (int c = 0; c < 2; ++c) {
            int idx = c * 512 + tid;
            int row = idx >> 3;
            gload_lds16(G + (size_t)(h * 128 + row) * K + k0 + s_lc * 8,
                        base + idx * 16);
        }
    };

    auto ldA = [&](int d, int row, int kk) -> sh8 {
        int half = row >> 7, lr = row & 127;
        int chp = (kk * 4 + (l >> 4)) ^ (l & 7);
        return *(const sh8*)(plds + d * 65536 + half * 16384 + lr * 128 + chp * 16);
    };
    auto ldB = [&](int d, int row, int kk) -> sh8 {
        int half = row >> 7, lr = row & 127;
        int chp = (kk * 4 + (l >> 4)) ^ (l & 7);
        return *(const sh8*)(plds + d * 65536 + 32768 + half * 16384 + lr * 128 + chp * 16);
    };

    const int nt = (kEnd - kBeg) / P_BK;    // even by construction

    stageH(0, 0, 0); stageH(0, 0, 1); stageH(0, 1, 0); stageH(0, 1, 1);
    if (nt > 1) {
        stageH(1, 1, 0); stageH(1, 1, 1);
        asm volatile("s_waitcnt vmcnt(4)" ::: "memory");
    } else {
        asm volatile("s_waitcnt vmcnt(0)" ::: "memory");
    }
    __builtin_amdgcn_s_barrier();
    __builtin_amdgcn_sched_barrier(0);

    sh8 bfr[4][2];
    for (int u = 0; u < nt; u += 2) {
        #pragma unroll
        for (int hv = 0; hv < 2; ++hv) {
            const int t = u + hv;
            const int d = t & 1;
            #pragma unroll
            for (int q = 0; q < 4; ++q) {
                const int i0 = 2 * q;
                int ra = wm * 128 + i0 * 16 + (l & 15);
                sh8 a00 = ldA(d, ra, 0);
                sh8 a01 = ldA(d, ra, 1);
                sh8 a10 = ldA(d, ra + 16, 0);
                sh8 a11 = ldA(d, ra + 16, 1);
                if (q == 0) {
                    #pragma unroll
                    for (int j = 0; j < 4; ++j) {
                        int rb = wn * 64 + j * 16 + (l & 15);
                        bfr[j][0] = ldB(d, rb, 0);
                        bfr[j][1] = ldB(d, rb, 1);
                    }
                }
                if (q == 0)      { if (t + 1 < nt) stageH(t + 1, 0, 0); }
                else if (q == 1) { if (t + 1 < nt) stageH(t + 1, 0, 1); }
                else if (q == 2) { if (t + 2 < nt) stageH(t + 2, 1, 0); }
                else             { if (t + 2 < nt) stageH(t + 2, 1, 1); }

                asm volatile("s_waitcnt lgkmcnt(0)" ::: "memory");
                __builtin_amdgcn_sched_barrier(0);
                __builtin_amdgcn_s_setprio(1);
                #pragma unroll
                for (int j = 0; j < 4; ++j) {
                    acc[i0][j] = __builtin_amdgcn_mfma_f32_16x16x32_bf16(
                                     a00, bfr[j][0], acc[i0][j], 0, 0, 0);
                    acc[i0][j] = __builtin_amdgcn_mfma_f32_16x16x32_bf16(
                                     a01, bfr[j][1], acc[i0][j], 0, 0, 0);
                    acc[i0 + 1][j] = __builtin_amdgcn_mfma_f32_16x16x32_bf16(
                                     a10, bfr[j][0], acc[i0 + 1][j], 0, 0, 0);
                    acc[i0 + 1][j] = __builtin_amdgcn_mfma_f32_16x16x32_bf16(
                                     a11, bfr[j][1], acc[i0 + 1][j], 0, 0, 0);
                }
                __builtin_amdgcn_s_setprio(0);
                if (q == 3) {
                    if (t + 2 < nt)      asm volatile("s_waitcnt vmcnt(4)" ::: "memory");
                    else if (t + 1 < nt) asm volatile("s_waitcnt vmcnt(0)" ::: "memory");
                }
                __builtin_amdgcn_s_barrier();
                __builtin_amdgcn_sched_barrier(0);
            }
        }
    }

    if (SPLITK) Cb += (size_t)blockIdx.z * M * N;

    const int crow0 = bm * P_BM + wm * 128;
    const int ccol0 = bn * P_BN + wn * 64;
    #pragma unroll
    for (int i = 0; i < 8; ++i) {
        #pragma unroll
        for (int j = 0; j < 4; ++j) {
            int col = ccol0 + j * 16 + (l & 15);
            float bia = BIAS ? bias[col] : 0.f;
            #pragma unroll
            for (int r = 0; r < 4; ++r) {
                int row = crow0 + i * 16 + (l >> 4) * 4 + r;
                float v = acc[i][j][r] + bia;
                if (SCALE) v *= scale;
                if (MASKMUL) v *= mask[(size_t)row * N + col];
                if (RELU) v = fmaxf(v, 0.f);
                if (OUTBF) Cb[(size_t)row * N + col] = f2bf(v);
                else       Cf[(size_t)row * N + col] = v;
            }
        }
    }
}

template<bool BIAS, bool RELU, bool SCALE, bool MASKMUL, bool OUTBF>
__global__ __launch_bounds__(512, 1)
void gemm8p_bt(const ushort_t* __restrict__ A, const ushort_t* __restrict__ Bt,
               const float* __restrict__ bias, const float* __restrict__ mask,
               float* __restrict__ Cf, ushort_t* __restrict__ Cb,
               int M, int N, int K, float scale)
{
    gemm8p_body<BIAS, RELU, SCALE, MASKMUL, OUTBF, false>(
        A, Bt, bias, mask, Cf, Cb, M, N, K, 0, K, scale);
}

__global__ __launch_bounds__(512, 1)
void gemm8p_bt_sk(const ushort_t* __restrict__ A, const ushort_t* __restrict__ Bt,
                  ushort_t* __restrict__ Cpart, int M, int N, int K, int Ks)
{
    int z = blockIdx.z;
    gemm8p_body<false, false, false, false, true, true>(
        A, Bt, nullptr, nullptr, nullptr, Cpart,
        M, N, K, z * Ks, z * Ks + Ks, 1.f);
}

// sum NS bf16 partial matrices, write bf16
template<int NS>
__global__ __launch_bounds__(256)
void reduce_sk(const ushort_t* __restrict__ parts, ushort_t* __restrict__ ob,
               size_t MN)
{
    size_t idx = ((size_t)blockIdx.x * 256 + threadIdx.x) * 8;
    float s[8] = {0.f, 0.f, 0.f, 0.f, 0.f, 0.f, 0.f, 0.f};
    #pragma unroll
    for (int p = 0; p < NS; ++p) {
        sh8 v = *(const sh8*)(parts + (size_t)p * MN + idx);
        #pragma unroll
        for (int j = 0; j < 8; ++j) s[j] += bf2f((ushort_t)v[j]);
    }
    sh8 r;
    #pragma unroll
    for (int j = 0; j < 8; ++j) r[j] = (short)f2bf(s[j]);
    *(sh8*)(ob + idx) = r;
}

// ---------------------------------------------------------------------------
// prep_all: merged prologue — cvt(query,key,value->bf16) + 4x DxD weight
// transpose + W1T + W2T in ONE launch. Flat grid 18432 x 256 thr.
// ---------------------------------------------------------------------------
__global__ __launch_bounds__(256)
void prep_all(const float* q, const float* k, const float* v,
              ushort_t* oq, ushort_t* ok, ushort_t* ov,
              const float* w0, const float* w1, const float* w2, const float* w3,
              ushort_t* o0, ushort_t* o1, ushort_t* o2, ushort_t* o3,
              const float* W1, ushort_t* W1T,
              const float* W2, ushort_t* W2T)
{
    __shared__ float t[32][33];
    int b = blockIdx.x;

    if (b < 6144) {                       // elementwise f32 -> bf16
        int y = b >> 11, x = b & 2047;
        const float* in = (y == 0) ? q : (y == 1) ? k : v;
        ushort_t* out   = (y == 0) ? oq : (y == 1) ? ok : ov;
        int i = (x * 256 + threadIdx.x) * 8;
        const float4* p = (const float4*)(in + i);
        float4 a = p[0], c = p[1];
        sh8 r;
        r[0] = (short)f2bf(a.x); r[1] = (short)f2bf(a.y);
        r[2] = (short)f2bf(a.z); r[3] = (short)f2bf(a.w);
        r[4] = (short)f2bf(c.x); r[5] = (short)f2bf(c.y);
        r[6] = (short)f2bf(c.z); r[7] = (short)f2bf(c.w);
        *(sh8*)(out + i) = r;
        return;
    }

    const float* in; ushort_t* out; int R, C, bx, by;
    if (b < 10240) {                      // 4 DxD transposes
        int b2 = b - 6144;
        int z = b2 >> 10, xy = b2 & 1023;
        bx = xy & 31; by = xy >> 5;
        R = D_DIM; C = D_DIM;
        in  = (z == 0) ? w0 : (z == 1) ? w1 : (z == 2) ? w2 : w3;
        out = (z == 0) ? o0 : (z == 1) ? o1 : (z == 2) ? o2 : o3;
    } else if (b < 14336) {               // W1 [D][F] -> [F][D]
        int b3 = b - 10240;
        bx = b3 & 127; by = b3 >> 7;
        R = D_DIM; C = F_DIM;
        in = W1; out = W1T;
    } else {                              // W2 [F][D] -> [D][F]
        int b4 = b - 14336;
        bx = b4 & 31; by = b4 >> 5;
        R = F_DIM; C = D_DIM;
        in = W2; out = W2T;
    }

    int bc = bx * 32, br = by * 32;
    int tx = threadIdx.x & 31, ty = threadIdx.x >> 5;
    #pragma unroll
    for (int i = 0; i < 32; i += 8)
        t[ty + i][tx] = in[(size_t)(br + ty + i) * C + bc + tx];
    __syncthreads();
    #pragma unroll
    for (int i = 0; i < 32; i += 8)
        out[(size_t)(bc + ty + i) * R + br + tx] = f2bf(t[tx][ty + i]);
}

// bf16 [R][C] -> bf16 [C][R] transpose (v^T)
__global__ __launch_bounds__(256)
void transpose_bf16(const ushort_t* __restrict__ in, ushort_t* __restrict__ out,
                    int R, int C)
{
    __shared__ ushort_t t[32][33];
    int bc = blockIdx.x * 32, br = blockIdx.y * 32;
    int tx = threadIdx.x & 31, ty = threadIdx.x >> 5;
    #pragma unroll
    for (int i = 0; i < 32; i += 8)
        t[ty + i][tx] = in[(size_t)(br + ty + i) * C + bc + tx];
    __syncthreads();
    #pragma unroll
    for (int i = 0; i < 32; i += 8)
        out[(size_t)(bc + ty + i) * R + br + tx] = t[tx][ty + i];
}

// ---------------------------------------------------------------------------
// Column softmax (axis 0) over m = masked scaled scores (bf16).
// Partials in [chunk][col] layout (coalesced both passes).
// ---------------------------------------------------------------------------
#define NCH 256
#define ROWS_PER_CH (S_DIM / NCH)   // 16

__global__ __launch_bounds__(256)
void smax_pass1(const ushort_t* __restrict__ m,
                float* __restrict__ pmax, float* __restrict__ psum)
{
    int c0 = (blockIdx.x * 256 + threadIdx.x) * 8;
    int chunk = blockIdx.y;
    int r0 = chunk * ROWS_PER_CH;

    float mx[8], sm[8];
    #pragma unroll
    for (int j = 0; j < 8; ++j) { mx[j] = -1e30f; sm[j] = 0.f; }

    for (int i = 0; i < ROWS_PER_CH; ++i) {
        size_t off = (size_t)(r0 + i) * S_DIM + c0;
        sh8 mv = *(const sh8*)(m + off);
        #pragma unroll
        for (int j = 0; j < 8; ++j) {
            float v = bf2f((ushort_t)mv[j]);
            float nm = fmaxf(mx[j], v);
            sm[j] = sm[j] * __expf(mx[j] - nm) + __expf(v - nm);
            mx[j] = nm;
        }
    }
    #pragma unroll
    for (int j = 0; j < 8; ++j) {
        pmax[(size_t)chunk * S_DIM + c0 + j] = mx[j];
        psum[(size_t)chunk * S_DIM + c0 + j] = sm[j];
    }
}

__global__ __launch_bounds__(256)
void smax_pass2(const float* __restrict__ pmax, const float* __restrict__ psum,
                float* __restrict__ cmax, float* __restrict__ cinv)
{
    int col = blockIdx.x * 256 + threadIdx.x;
    float mx = -1e30f, sm = 0.f;
    for (int c = 0; c < NCH; ++c) {
        float m2 = pmax[(size_t)c * S_DIM + col];
        float s2 = psum[(size_t)c * S_DIM + col];
        float nm = fmaxf(mx, m2);
        sm = sm * __expf(mx - nm) + s2 * __expf(m2 - nm);
        mx = nm;
    }
    cmax[col] = mx;
    cinv[col] = 1.f / sm;
}

__global__ __launch_bounds__(256)
void smax_pass3(const ushort_t* __restrict__ m,
                const float* __restrict__ cmax, const float* __restrict__ cinv,
                ushort_t* __restrict__ h)
{
    size_t idx = ((size_t)blockIdx.x * 256 + threadIdx.x) * 8;
    int col0 = (int)(idx & (S_DIM - 1));
    sh8 mv = *(const sh8*)(m + idx);
    sh8 r;
    #pragma unroll
    for (int j = 0; j < 8; ++j) {
        int c = col0 + j;
        float v = bf2f((ushort_t)mv[j]);
        r[j] = (short)f2bf(__expf(v - cmax[c]) * cinv[c]);
    }
    *(sh8*)(h + idx) = r;
}

// ---------------------------------------------------------------------------
// LayerNorm( sum(parts) + pbias + resid ) over D=1024, one row per block.
// ---------------------------------------------------------------------------
template<int NS, bool WB>
__global__ __launch_bounds__(256)
void add_ln_sk(const ushort_t* __restrict__ parts, const float* __restrict__ pbias,
               const float* __restrict__ resid, const float* __restrict__ g,
               const float* __restrict__ be,
               float* __restrict__ of, ushort_t* __restrict__ ob)
{
    const int D = D_DIM;
    const size_t SD = (size_t)S_DIM * D_DIM;
    int row = blockIdx.x, tid = threadIdx.x;
    size_t base = (size_t)row * D + tid * 4;

    float4 vr = *(const float4*)(resid + base);
    float4 vbi = ((const float4*)pbias)[tid];
    float x0 = vr.x + vbi.x, x1 = vr.y + vbi.y, x2 = vr.z + vbi.z, x3 = vr.w + vbi.w;
    #pragma unroll
    for (int p = 0; p < NS; ++p) {
        sh4 v = *(const sh4*)(parts + p * SD + base);
        x0 += bf2f((ushort_t)v[0]); x1 += bf2f((ushort_t)v[1]);
        x2 += bf2f((ushort_t)v[2]); x3 += bf2f((ushort_t)v[3]);
    }

    float s = x0 + x1 + x2 + x3;
    float q = x0 * x0 + x1 * x1 + x2 * x2 + x3 * x3;
    #pragma unroll
    for (int off = 32; off; off >>= 1) {
        s += __shfl_down(s, off);
        q += __shfl_down(q, off);
    }
    __shared__ float red[8];
    int w = tid >> 6, l = tid & 63;
    if (!l) { red[w] = s; red[4 + w] = q; }
    __syncthreads();
    s = red[0] + red[1] + red[2] + red[3];
    q = red[4] + red[5] + red[6] + red[7];
    float mu = s * (1.f / D);
    float rstd = rsqrtf(q * (1.f / D) - mu * mu + 1e-5f);
    float4 vg  = ((const float4*)g)[tid];
    float4 vbe = ((const float4*)be)[tid];
    float y0 = (x0 - mu) * rstd * vg.x + vbe.x;
    float y1 = (x1 - mu) * rstd * vg.y + vbe.y;
    float y2 = (x2 - mu) * rstd * vg.z + vbe.z;
    float y3 = (x3 - mu) * rstd * vg.w + vbe.w;
    float4 r; r.x = y0; r.y = y1; r.z = y2; r.w = y3;
    *(float4*)(of + base) = r;
    if (WB) {
        sh4 rb;
        rb[0] = (short)f2bf(y0); rb[1] = (short)f2bf(y1);
        rb[2] = (short)f2bf(y2); rb[3] = (short)f2bf(y3);
        *(sh4*)(ob + base) = rb;
    }
}

// ---------------------------------------------------------------------------
extern "C" void kernel_launch(void* const* d_in, const int* in_sizes, int n_in,
                              void* d_out, int out_size, void* d_ws, size_t ws_size,
                              hipStream_t stream)
{
    const float* query = (const float*)d_in[0];
    const float* key_  = (const float*)d_in[1];
    const float* value = (const float*)d_in[2];
    const float* mask  = (const float*)d_in[3];
    const float* Wq = (const float*)d_in[4];  const float* bq = (const float*)d_in[5];
    const float* Wk = (const float*)d_in[6];  const float* bk = (const float*)d_in[7];
    const float* Wv = (const float*)d_in[8];  const float* bv = (const float*)d_in[9];
    const float* Wo = (const float*)d_in[10]; const float* bo = (const float*)d_in[11];
    const float* g1 = (const float*)d_in[12]; const float* be1 = (const float*)d_in[13];
    const float* W1 = (const float*)d_in[14]; const float* bf1 = (const float*)d_in[15];
    const float* W2 = (const float*)d_in[16]; const float* bf2 = (const float*)d_in[17];
    const float* g2 = (const float*)d_in[18]; const float* be2 = (const float*)d_in[19];

    const size_t MB = 1ull << 20;
    char* ws = (char*)d_ws;
    ushort_t* WqT = (ushort_t*)(ws);             // [0,2)
    ushort_t* WkT = (ushort_t*)(ws + 2 * MB);    // [2,4)
    ushort_t* WvT = (ushort_t*)(ws + 4 * MB);    // [4,6)
    ushort_t* WoT = (ushort_t*)(ws + 6 * MB);    // [6,8)
    ushort_t* W1T = (ushort_t*)(ws + 8 * MB);    // [8,16)   [F][D]
    ushort_t* W2T = (ushort_t*)(ws + 16 * MB);   // [16,24)  [D][F]
    ushort_t* qin = (ushort_t*)(ws + 24 * MB);   // [24,32)
    ushort_t* kin = (ushort_t*)(ws + 32 * MB);   // [32,40)
    ushort_t* vin = (ushort_t*)(ws + 40 * MB);   // [40,48)
    ushort_t* qb  = (ushort_t*)(ws + 48 * MB);   // [48,56)
    ushort_t* kb  = (ushort_t*)(ws + 56 * MB);   // [56,64)
    ushort_t* vb  = (ushort_t*)(ws + 64 * MB);   // [64,72)
    ushort_t* vT  = (ushort_t*)(ws + 72 * MB);   // [72,80)  [D][S]
    ushort_t* msc = (ushort_t*)(ws + 80 * MB);   // [80,112) masked scaled scores
    ushort_t* hb  = (ushort_t*)(ws + 112 * MB);  // [112,144)
    float*   pmax = (float*)(ws + 144 * MB);     // [144,148) [NCH][S]
    float*   psum = (float*)(ws + 148 * MB);     // [148,152)
    float*   cmax = (float*)(ws + 152 * MB);
    float*   cinv = (float*)(ws + 152 * MB + 64 * 1024);
    // reused regions
    ushort_t* pts1  = (ushort_t*)(ws + 80 * MB); // h@v partials 4x8MB over msc
    ushort_t* apb   = (ushort_t*)(ws + 24 * MB); // attn_pre bf16 over qin
    ushort_t* pts2  = (ushort_t*)(ws + 80 * MB); // attn@Wo partials 2x8MB
    float*    n1f   = (float*)(ws + 48 * MB);    // over qb+kb
    ushort_t* n1b   = (ushort_t*)(ws + 64 * MB); // over vb
    ushort_t* mid   = (ushort_t*)(ws + 112 * MB);// [S][F] bf16 over hb
    ushort_t* pts3  = (ushort_t*)(ws + 80 * MB); // ff partials 4x8MB

    const int S = S_DIM, D = D_DIM, F = F_DIM;
    const size_t P_LDS = 131072;

    // 1. merged prologue: cvt x3 + all weight transposes (one launch)
    prep_all<<<18432, 256, 0, stream>>>(
        query, key_, value, qin, kin, vin,
        Wq, Wk, Wv, Wo, WqT, WkT, WvT, WoT,
        W1, W1T, W2, W2T);

    // 2. batched q,k,v projections (128², 768 blocks)
    qkv_gemm<<<dim3(S / BM, D / BN, 3), 256, 0, stream>>>(
        qin, kin, vin, WqT, WkT, WvT, bq, bk, bv, qb, kb, vb, S, D, D);

    // 3. v^T bf16 [D][S]
    transpose_bf16<<<dim3(D / 32, S / 32), 256, 0, stream>>>(vb, vT, S, D);

    // 4. masked scaled scores — 8-phase 256² kernel, grid (16,16)
    gemm8p_bt<false, false, true, true, true>
        <<<dim3(S / P_BM, S / P_BN), 512, P_LDS, stream>>>(
        qb, kb, nullptr, mask, nullptr, msc, S, S, D, 0.03125f);

    // 5. column softmax (msc already masked)
    smax_pass1<<<dim3(S / 2048, NCH), 256, 0, stream>>>(msc, pmax, psum);
    smax_pass2<<<S / 256, 256, 0, stream>>>(pmax, psum, cmax, cinv);
    smax_pass3<<<(size_t)S * S / 8 / 256, 256, 0, stream>>>(msc, cmax, cinv, hb);

    // 6. attn_pre = h @ v — 8-phase 256², 4-way split-K
    gemm8p_bt_sk<<<dim3(S / P_BM, D / P_BN, 4), 512, P_LDS, stream>>>(
        hb, vT, pts1, S, D, S, S / 4);
    reduce_sk<4><<<S * D / 2048, 256, 0, stream>>>(pts1, apb, (size_t)S * D);

    // 7. attn partials = attn_pre @ Wo — 128², 2-way split-K
    gemm_bt_sk<<<dim3(S / BM, D / BN, 2), 256, 0, stream>>>(apb, WoT, pts2, S, D, D, D / 2);

    // 8. n1 = LN(sum(pts2) + bo + query)
    add_ln_sk<2, true><<<S, 256, 0, stream>>>(pts2, bo, query, g1, be1, n1f, n1b);

    // 9. mid = relu(n1 @ W1 + bf1) — 8-phase 256²
    gemm8p_bt<true, true, false, false, true>
        <<<dim3(S / P_BM, F / P_BN), 512, P_LDS, stream>>>(
        n1b, W1T, bf1, nullptr, nullptr, mid, S, F, D, 1.f);

    // 10. ff partials = mid @ W2 — 8-phase 256², 4-way split-K
    gemm8p_bt_sk<<<dim3(S / P_BM, D / P_BN, 4), 512, P_LDS, stream>>>(
        mid, W2T, pts3, S, D, F, F / 4);

    // 11. out = LN(sum(pts3) + bf2 + n1)
    add_ln_sk<4, false><<<S, 256, 0, stream>>>(pts3, bf2, n1f, g2, be2,
                                               (float*)d_out, nullptr);
}